// Round 4
// baseline (24104.048 us; speedup 1.0000x reference)
//
#include <hip/hip_runtime.h>
#include <cstddef>
#include <math.h>

// Problem: B=64, S=1024, F=128, H=512, V=64, T=64. All floats f32; out f32.
// Design: 32 persistent WGs; W_hh hi/lo f16 Ootomo fragments register-resident;
// cross-WG h exchange via RELAXED AGENT-SCOPE ATOMICS (sc0 sc1: loads bypass
// L1/L2 and read the coherence point; stores write through). This removes ALL
// per-step cache-maintenance fences (R3's buffer_wbl2/buffer_inv per WG per
// step were the 20us/step cost: L2 wiped every step -> 700MB HBM refetch).
// Barrier = __syncthreads (drains vmcnt => write-through stores visible) +
// relaxed fetch_add + relaxed poll. Read-only data stays L2-warm.
#define NWG 32
#define BB  64
#define HH  512
#define TT  64
#define VV  64
#define FF  128
#define SS  1024

typedef _Float16 f16;
typedef _Float16 f16x8 __attribute__((ext_vector_type(8)));
typedef float    f32x4 __attribute__((ext_vector_type(4)));
typedef unsigned long long u64;

#define C1 4.8828125e-4f          // 2^-11
#define C2 2.384185791015625e-7f  // 2^-22

__device__ __forceinline__ void split8(const float* __restrict__ p, f16x8& hi, f16x8& lo) {
  f32x4 u = *(const f32x4*)p;
  f32x4 v = *(const f32x4*)(p + 4);
#pragma unroll
  for (int j = 0; j < 4; ++j) {
    f16 a = (f16)u[j]; hi[j]   = a; lo[j]   = (f16)((u[j] - (float)a) * 2048.0f);
    f16 b = (f16)v[j]; hi[4+j] = b; lo[4+j] = (f16)((v[j] - (float)b) * 2048.0f);
  }
}
__device__ __forceinline__ f16x8 ldh8(const f16* p) { return *(const f16x8*)p; }
__device__ __forceinline__ float sigmf_(float x) { return 1.0f / (1.0f + expf(-x)); }

// ---- coherent (agent-scope, relaxed) 8B/4B accessors: sc0 sc1, no fences ----
__device__ __forceinline__ u64 lda8(const void* p) {
  return __hip_atomic_load((const u64*)p, __ATOMIC_RELAXED, __HIP_MEMORY_SCOPE_AGENT);
}
__device__ __forceinline__ void sta8(void* p, u64 v) {
  __hip_atomic_store((u64*)p, v, __ATOMIC_RELAXED, __HIP_MEMORY_SCOPE_AGENT);
}
__device__ __forceinline__ unsigned lda4(const unsigned* p) {
  return __hip_atomic_load(p, __ATOMIC_RELAXED, __HIP_MEMORY_SCOPE_AGENT);
}
__device__ __forceinline__ void sta4(unsigned* p, unsigned v) {
  __hip_atomic_store(p, v, __ATOMIC_RELAXED, __HIP_MEMORY_SCOPE_AGENT);
}
__device__ __forceinline__ f16x8 ldh8c(const f16* p) {   // 16B via 2x8B atomic
  union { u64 u[2]; f16x8 v; } r;
  r.u[0] = lda8(p);
  r.u[1] = lda8(p + 4);
  return r.v;
}

// ---- grid barrier: NO cache maintenance (all shared data goes via atomics) --
__device__ __forceinline__ void g_arrive(unsigned* cnt) {
  __syncthreads();   // s_waitcnt vmcnt(0) before s_barrier: our sc1 stores done
  if (threadIdx.x == 0)
    __hip_atomic_fetch_add(cnt, 1u, __ATOMIC_RELAXED, __HIP_MEMORY_SCOPE_AGENT);
}
__device__ __forceinline__ void g_wait(unsigned* cnt, unsigned target) {
  if (threadIdx.x == 0) {
    while (__hip_atomic_load(cnt, __ATOMIC_RELAXED, __HIP_MEMORY_SCOPE_AGENT) < target)
      __builtin_amdgcn_s_sleep(1);
  }
  __syncthreads();
}

#define MFMA(d, a, b) d = __builtin_amdgcn_mfma_f32_16x16x32_f16(a, b, d, 0, 0, 0)

// h-part: load 4 K-steps (4 fragments each) into register buffer pp
#define HLOAD(pp, c)                                                        \
  _Pragma("unroll") for (int s2 = 0; s2 < 4; ++s2) {                        \
    const int s = (c)*4 + s2;                                               \
    fa[pp][s2][0] = ldh8c(h0h + s*32 + q8);                                 \
    fa[pp][s2][1] = ldh8c(h0l + s*32 + q8);                                 \
    fa[pp][s2][2] = ldh8c(h0h + 16*HH + s*32 + q8);                         \
    fa[pp][s2][3] = ldh8c(h0l + 16*HH + s*32 + q8);                         \
  }
#define HCOMP(pp, c)                                                        \
  _Pragma("unroll") for (int s2 = 0; s2 < 4; ++s2) {                        \
    const int s = (c)*4 + s2;                                               \
    _Pragma("unroll") for (int nt = 0; nt < 2; ++nt) {                      \
      MFMA(acc0[0+nt], fa[pp][s2][0], fhhh[nt][s]);                         \
      MFMA(acc0[2+nt], fa[pp][s2][2], fhhh[nt][s]);                         \
      MFMA(acc1[0+nt], fa[pp][s2][1], fhhh[nt][s]);                         \
      MFMA(acc1[2+nt], fa[pp][s2][3], fhhh[nt][s]);                         \
      MFMA(acc1[0+nt], fa[pp][s2][0], fhhl[nt][s]);                         \
      MFMA(acc1[2+nt], fa[pp][s2][2], fhhl[nt][s]);                         \
      MFMA(acc2[0+nt], fa[pp][s2][1], fhhl[nt][s]);                         \
      MFMA(acc2[2+nt], fa[pp][s2][3], fhhl[nt][s]);                         \
    }                                                                       \
  }
#define HPART_ALL()                                                         \
  { HLOAD(0, 0) HLOAD(1, 1) HCOMP(0, 0) HLOAD(0, 2) HCOMP(1, 1)             \
    HLOAD(1, 3) HCOMP(0, 2) HCOMP(1, 3) }

__global__ void __launch_bounds__(256, 1) lstm_seq2seq(
    const float* __restrict__ sig,   // [B,S,F]
    const int*   __restrict__ tgt,   // [B,T]
    const float* __restrict__ eWih,  // [2048,128]
    const float* __restrict__ eWhh,  // [2048,512]
    const float* __restrict__ eBih,  // [2048]
    const float* __restrict__ eBhh,  // [2048]
    const float* __restrict__ dWih,  // [2048,64]
    const float* __restrict__ dWhh,  // [2048,512]
    const float* __restrict__ dBih,  // [2048]
    const float* __restrict__ dBhh,  // [2048]
    const float* __restrict__ oW,    // [64,512]
    const float* __restrict__ oB,    // [64]
    float*       __restrict__ out,   // [B,T,V]
    unsigned char* __restrict__ ws)
{
  unsigned* cnt    = (unsigned*)ws;
  unsigned* idxbuf = (unsigned*)(ws + 256);
  f16* hhi[2] = { (f16*)(ws + 1024),   (f16*)(ws + 1024 + 65536) };
  f16* hlo[2] = { (f16*)(ws + 132096), (f16*)(ws + 132096 + 65536) };
  float* hf32[2] = { (float*)(ws + 263168), (float*)(ws + 263168 + 131072) };

  const int tid   = threadIdx.x;
  const int p     = blockIdx.x;     // WG owns h-dims [p*16, p*16+16) per gate
  const int w     = tid >> 6;
  const int lane  = tid & 63;
  const int q     = lane >> 4;      // MFMA quad: A/B k = q*8+j ; C/D row = q*4+r
  const int mn    = lane & 15;      // A row (m) / B col (n) / C col
  const int q8    = q * 8;
  const int bhalf = w >> 1;         // batch rows [bhalf*32, +32)
  const int dhalf = w & 1;          // local gate-dims [dhalf*32, +32)

  __shared__ f16 xwh[64][136];      // eWih slice hi (pad 8: no 2^k stride)
  __shared__ f16 xwl[64][136];      // eWih slice lo (x2048)
  __shared__ float gate_buf[4][64][17];
  __shared__ float bias_buf[4][16];

  // ---- encoder weights: W_hh hi/lo fragments in registers ----
  f16x8 fhhh[2][16], fhhl[2][16];
#pragma unroll
  for (int nt = 0; nt < 2; ++nt) {
    int dl  = dhalf*32 + nt*16 + mn;             // local gate-dim 0..63
    int row = (dl >> 4)*HH + p*16 + (dl & 15);   // row of W [4H x K]
#pragma unroll
    for (int s = 0; s < 16; ++s)
      split8(eWhh + (size_t)row*HH + s*32 + q8, fhhh[nt][s], fhhl[nt][s]);
  }
  for (int idx = tid; idx < 64*128; idx += 256) {
    int dl = idx >> 7, k = idx & 127;
    int row = (dl >> 4)*HH + p*16 + (dl & 15);
    float x = eWih[row*FF + k];
    f16 a = (f16)x;
    xwh[dl][k] = a;
    xwl[dl][k] = (f16)((x - (float)a) * 2048.0f);
  }
  if (tid < 64) {
    int g = tid >> 4, kl = tid & 15;
    int r = g*HH + p*16 + kl;
    bias_buf[g][kl] = eBih[r] + eBhh[r];
  }
  if (p == 0 && tid < 64) sta4(idxbuf + tid, (unsigned)tgt[tid * TT]); // target[:,0]
  __syncthreads();

  float c_reg[4] = {0.f, 0.f, 0.f, 0.f};
  const int eb  = tid >> 2;          // cell batch
  const int ek0 = (tid & 3) * 4;     // cell k-local base
  const int off0 = eb*HH + p*16 + ek0;   // 8B-aligned (ek0 % 4 == 0)

  int cur = 0;                       // h double buffer (zeroed by memset = h0)
  const f32x4 zero4 = {0.f, 0.f, 0.f, 0.f};

  // ================= encoder: 1024 steps =================
  for (int t = 0; t < SS; ++t) {
    f32x4 acc0[4] = {zero4, zero4, zero4, zero4};   // [rt*2+nt]
    f32x4 acc1[4] = {zero4, zero4, zero4, zero4};
    f32x4 acc2[4] = {zero4, zero4, zero4, zero4};

    // ---- x part (K=128): independent of h(t) -> overlaps barrier wait ----
    const float* sb0 = sig + (size_t)(bhalf*32 + mn)*(SS*FF) + (size_t)t*FF;
    const float* sb1 = sb0 + (size_t)16*(SS*FF);
#pragma unroll
    for (int s = 0; s < 4; ++s) {
      f16x8 a0h, a0l, a1h, a1l;
      split8(sb0 + s*32 + q8, a0h, a0l);
      split8(sb1 + s*32 + q8, a1h, a1l);
#pragma unroll
      for (int nt = 0; nt < 2; ++nt) {
        int dl = dhalf*32 + nt*16 + mn;
        f16x8 bh = ldh8(&xwh[dl][s*32 + q8]);
        f16x8 bl = ldh8(&xwl[dl][s*32 + q8]);
        MFMA(acc0[0+nt], a0h, bh);  MFMA(acc0[2+nt], a1h, bh);
        MFMA(acc1[0+nt], a0l, bh);  MFMA(acc1[2+nt], a1l, bh);
        MFMA(acc1[0+nt], a0h, bl);  MFMA(acc1[2+nt], a1h, bl);
        MFMA(acc2[0+nt], a0l, bl);  MFMA(acc2[2+nt], a1l, bl);
      }
    }
    // ---- h(t) now needed ----
    g_wait(cnt, (unsigned)t * NWG);
    {
      const f16* h0h = hhi[cur] + (bhalf*32 + mn)*HH;
      const f16* h0l = hlo[cur] + (bhalf*32 + mn)*HH;
      f16x8 fa[2][4][4];
      HPART_ALL()
    }
    // combine splits -> f32 gates, exchange via LDS (C/D: col=mn, row=q*4+r)
#pragma unroll
    for (int rt = 0; rt < 2; ++rt)
#pragma unroll
      for (int nt = 0; nt < 2; ++nt) {
        int i = rt*2 + nt;
#pragma unroll
        for (int r = 0; r < 4; ++r) {
          float g = acc0[i][r] + C1*acc1[i][r] + C2*acc2[i][r];
          gate_buf[dhalf*2 + nt][bhalf*32 + rt*16 + q*4 + r][mn] = g;
        }
      }
    __syncthreads();
    // LSTM cell on owned cells (f32, precise libm)
    {
      union { f16 h[4]; u64 u; } ph, pl;
#pragma unroll
      for (int j = 0; j < 4; ++j) {
        int kl = ek0 + j;
        float gi = gate_buf[0][eb][kl] + bias_buf[0][kl];
        float gf = gate_buf[1][eb][kl] + bias_buf[1][kl];
        float gg = gate_buf[2][eb][kl] + bias_buf[2][kl];
        float go = gate_buf[3][eb][kl] + bias_buf[3][kl];
        float c  = sigmf_(gf)*c_reg[j] + sigmf_(gi)*tanhf(gg);
        float h  = sigmf_(go)*tanhf(c);
        c_reg[j] = c;
        f16 hh = (f16)h;
        ph.h[j] = hh;
        pl.h[j] = (f16)((h - (float)hh) * 2048.0f);
      }
      sta8(hhi[cur^1] + off0, ph.u);
      sta8(hlo[cur^1] + off0, pl.u);
    }
    g_arrive(cnt);                 // signals h(t+1) ready  [arrival #(t+1)]
    cur ^= 1;
  }

  // ================= decoder setup (read-only loads; no barrier needed) ====
#pragma unroll
  for (int nt = 0; nt < 2; ++nt) {
    int dl  = dhalf*32 + nt*16 + mn;
    int row = (dl >> 4)*HH + p*16 + (dl & 15);
#pragma unroll
    for (int s = 0; s < 16; ++s)
      split8(dWhh + (size_t)row*HH + s*32 + q8, fhhh[nt][s], fhhl[nt][s]);
  }
  __syncthreads();   // bias_buf rewrite: no wave may still read enc biases
  if (tid < 64) {
    int g = tid >> 4, kl = tid & 15;
    int r = g*HH + p*16 + kl;
    bias_buf[g][kl] = dBih[r] + dBhh[r];
  }
  __syncthreads();

  // ================= decoder: 64 steps =================
  for (int t = 0; t < TT; ++t) {
    // ---- phase A: cell. x = relu(one_hot(idx)) = one_hot -> column gather ----
    g_wait(cnt, (unsigned)(SS + 2*t) * NWG);    // h(dec t) + idx(t) visible
    f32x4 acc0[4] = {zero4, zero4, zero4, zero4};
    f32x4 acc1[4] = {zero4, zero4, zero4, zero4};
    f32x4 acc2[4] = {zero4, zero4, zero4, zero4};
    {
      const f16* h0h = hhi[cur] + (bhalf*32 + mn)*HH;
      const f16* h0l = hlo[cur] + (bhalf*32 + mn)*HH;
      f16x8 fa[2][4][4];
      HPART_ALL()
    }
#pragma unroll
    for (int rt = 0; rt < 2; ++rt)
#pragma unroll
      for (int nt = 0; nt < 2; ++nt) {
        int i = rt*2 + nt;
#pragma unroll
        for (int r = 0; r < 4; ++r) {
          float g = acc0[i][r] + C1*acc1[i][r] + C2*acc2[i][r];
          gate_buf[dhalf*2 + nt][bhalf*32 + rt*16 + q*4 + r][mn] = g;
        }
      }
    __syncthreads();
    {
      int ib = (int)lda4(idxbuf + eb);
      union { f16 h[4]; u64 u; } ph, pl;
      union { float f[2]; u64 u; } pf0, pf1;
#pragma unroll
      for (int j = 0; j < 4; ++j) {
        int kl = ek0 + j;
        int rb = p*16 + kl;
        float gi = gate_buf[0][eb][kl] + bias_buf[0][kl] + dWih[(0*HH + rb)*VV + ib];
        float gf = gate_buf[1][eb][kl] + bias_buf[1][kl] + dWih[(1*HH + rb)*VV + ib];
        float gg = gate_buf[2][eb][kl] + bias_buf[2][kl] + dWih[(2*HH + rb)*VV + ib];
        float go = gate_buf[3][eb][kl] + bias_buf[3][kl] + dWih[(3*HH + rb)*VV + ib];
        float c  = sigmf_(gf)*c_reg[j] + sigmf_(gi)*tanhf(gg);
        float h  = sigmf_(go)*tanhf(c);
        c_reg[j] = c;
        f16 hh = (f16)h;
        ph.h[j] = hh;
        pl.h[j] = (f16)((h - (float)hh) * 2048.0f);
        if (j < 2) pf0.f[j] = h; else pf1.f[j-2] = h;
      }
      sta8(hhi[cur^1] + off0, ph.u);
      sta8(hlo[cur^1] + off0, pl.u);
      sta8(hf32[cur^1] + off0,     pf0.u);
      sta8(hf32[cur^1] + off0 + 2, pf1.u);
    }
    g_arrive(cnt);                               // arrival #(SS + 2t + 1)
    int nxt = cur ^ 1;
    g_wait(cnt, (unsigned)(SS + 2*t + 1) * NWG); // hf32(nxt) visible

    // ---- phase B: f64 logits + argmax + log-softmax (waves 0,1; 1 row/wave)
    // (math kept bit-identical to R2/R3: single f64 acc, same order)
    if (w < 2) {
      int b = p*2 + w;
      int v = lane;
      const float* hp = hf32[nxt] + b*HH;
      const float* wr = oW + v*HH;
      double acc = 0.0;
#pragma unroll 4
      for (int kc = 0; kc < 128; ++kc) {
        union { u64 u[2]; f32x4 v4; } hv;
        hv.u[0] = lda8(hp + kc*4);
        hv.u[1] = lda8(hp + kc*4 + 2);
        f32x4 wv = *(const f32x4*)(wr + kc*4);
        acc += (double)hv.v4[0]*(double)wv[0] + (double)hv.v4[1]*(double)wv[1]
             + (double)hv.v4[2]*(double)wv[2] + (double)hv.v4[3]*(double)wv[3];
      }
      double l = acc + (double)oB[v];
      double mx = l; int ai = v;
#pragma unroll
      for (int o = 32; o > 0; o >>= 1) {
        double om = __shfl_xor(mx, o, 64);
        int    oi = __shfl_xor(ai, o, 64);
        if (om > mx || (om == mx && oi < ai)) { mx = om; ai = oi; }
      }
      double se = exp(l - mx);
#pragma unroll
      for (int o = 32; o > 0; o >>= 1) se += __shfl_xor(se, o, 64);
      double lse = mx + log(se);
      out[((size_t)b*TT + t)*VV + v] = (float)(l - lse);
      if (lane == 0) sta4(idxbuf + b, (unsigned)ai);
    }
    g_arrive(cnt);                               // arrival #(SS + 2t + 2)
    cur = nxt;
  }
}

extern "C" void kernel_launch(void* const* d_in, const int* in_sizes, int n_in,
                              void* d_out, int out_size, void* d_ws, size_t ws_size,
                              hipStream_t stream) {
  (void)in_sizes; (void)n_in; (void)out_size; (void)ws_size;
  // zero: counter + idxbuf + h16 hi/lo double-buffers + hf32 double-buffer
  // (ws is re-poisoned 0xAA before every launch -> must zero every call;
  //  memset data is globally visible: blit kernel ends with system release)
  size_t zbytes = 263168 + 262144;  // = 525312
  hipMemsetAsync(d_ws, 0, zbytes, stream);
  lstm_seq2seq<<<dim3(NWG), dim3(256), 0, stream>>>(
      (const float*)d_in[0],  (const int*)d_in[1],
      (const float*)d_in[2],  (const float*)d_in[3],
      (const float*)d_in[4],  (const float*)d_in[5],
      (const float*)d_in[6],  (const float*)d_in[7],
      (const float*)d_in[8],  (const float*)d_in[9],
      (const float*)d_in[10], (const float*)d_in[11],
      (float*)d_out, (unsigned char*)d_ws);
}

// Round 6
// 11972.707 us; speedup vs baseline: 2.0132x; 2.0132x over previous
//
#include <hip/hip_runtime.h>
#include <cstddef>
#include <math.h>

// Problem: B=64, S=1024, F=128, H=512, V=64, T=64. All floats f32; out f32.
// R6 design (placement-agnostic, R4-proven visibility):
//  - 32 persistent WGs; W_hh hi/lo f16 Ootomo fragments register-resident.
//  - h exchange: stores = relaxed agent atomics (write-through, R4-proven);
//    loads = explicit `global_load_dwordx4 sc0 sc1` asm (bypass L1/L2, read
//    coherence point) -- guaranteed BATCHED in flight, unlike atomic-load
//    codegen which R4 evidence suggests serialized (~64 far loads/lane/step
//    x ~900cyc ~= the 21us/step R2-R4 all showed).
//  - h staged to LDS once per WG (kills the 2x dhalf-wave redundancy):
//    4 chunks of K=128, double-buffered, chunk c+1 global loads overlap
//    chunk c MFMA.
//  - barrier: per-WG flag array (128B stride), arrival = 1 relaxed store
//    (no same-address RMW serialization), detection = 64-lane gather poll.
#define NWG 32
#define BB  64
#define HH  512
#define TT  64
#define VV  64
#define FF  128
#define SS  1024

typedef _Float16 f16;
typedef _Float16 f16x8 __attribute__((ext_vector_type(8)));
typedef float    f32x4 __attribute__((ext_vector_type(4)));
typedef unsigned long long u64;

#define C1 4.8828125e-4f          // 2^-11
#define C2 2.384185791015625e-7f  // 2^-22

__device__ __forceinline__ void split8(const float* __restrict__ p, f16x8& hi, f16x8& lo) {
  f32x4 u = *(const f32x4*)p;
  f32x4 v = *(const f32x4*)(p + 4);
#pragma unroll
  for (int j = 0; j < 4; ++j) {
    f16 a = (f16)u[j]; hi[j]   = a; lo[j]   = (f16)((u[j] - (float)a) * 2048.0f);
    f16 b = (f16)v[j]; hi[4+j] = b; lo[4+j] = (f16)((v[j] - (float)b) * 2048.0f);
  }
}
__device__ __forceinline__ f16x8 ldh8(const f16* p) { return *(const f16x8*)p; }
__device__ __forceinline__ float sigmf_(float x) { return 1.0f / (1.0f + expf(-x)); }

// far (coherence-point) accessors
__device__ __forceinline__ f32x4 ld16f(const void* p) {      // batched far load
  f32x4 r;
  asm volatile("global_load_dwordx4 %0, %1, off sc0 sc1" : "=v"(r) : "v"(p) : "memory");
  return r;
}
__device__ __forceinline__ void st8f(void* p, u64 v) {
  __hip_atomic_store((u64*)p, v, __ATOMIC_RELAXED, __HIP_MEMORY_SCOPE_AGENT);
}
__device__ __forceinline__ unsigned ld4f(const unsigned* p) {
  return __hip_atomic_load(p, __ATOMIC_RELAXED, __HIP_MEMORY_SCOPE_AGENT);
}
__device__ __forceinline__ void st4f(unsigned* p, unsigned v) {
  __hip_atomic_store(p, v, __ATOMIC_RELAXED, __HIP_MEMORY_SCOPE_AGENT);
}
#define VMWAIT asm volatile("s_waitcnt vmcnt(0)" ::: "memory")

// barrier: poll all 32 per-WG flags with one 64-lane gather per iteration
__device__ __forceinline__ void wait_flags(const unsigned* flags, unsigned target, int lane) {
  const unsigned* a = flags + (size_t)(lane & 31) * 32;   // 128B stride
  while (!__all(ld4f(a) >= target))
    __builtin_amdgcn_s_sleep(1);
}

#define MFMA(d, a, b) d = __builtin_amdgcn_mfma_f32_16x16x32_f16(a, b, d, 0, 0, 0)

// ---- staged h machinery: chunk = K-range [c*128, c*128+128) ----
#define STAGE_ISSUE(c)                                                   \
  _Pragma("unroll") for (int u = 0; u < 4; ++u) {                        \
    int un = sk + 4*u;                                                   \
    vh[u] = ld16f(ghi + (size_t)sr*HH + (c)*128 + un*8);                 \
    vl[u] = ld16f(glo + (size_t)sr*HH + (c)*128 + un*8);                 \
  }
#define STAGE_WRITE(buf)                                                 \
  _Pragma("unroll") for (int u = 0; u < 4; ++u) {                        \
    int un = sk + 4*u;                                                   \
    *(f32x4*)&shi[buf][sr][un*8] = vh[u];                                \
    *(f32x4*)&slo[buf][sr][un*8] = vl[u];                                \
  }
#define HCHUNK(buf, c)                                                   \
  _Pragma("unroll") for (int s2 = 0; s2 < 4; ++s2) {                     \
    const int s = (c)*4 + s2;                                            \
    f16x8 a0h = ldh8(&shi[buf][r0][s2*32 + q8]);                         \
    f16x8 a0l = ldh8(&slo[buf][r0][s2*32 + q8]);                         \
    f16x8 a1h = ldh8(&shi[buf][r1][s2*32 + q8]);                         \
    f16x8 a1l = ldh8(&slo[buf][r1][s2*32 + q8]);                         \
    _Pragma("unroll") for (int nt = 0; nt < 2; ++nt) {                   \
      MFMA(acc0[0+nt], a0h, fhhh[nt][s]);                                \
      MFMA(acc0[2+nt], a1h, fhhh[nt][s]);                                \
      MFMA(acc1[0+nt], a0l, fhhh[nt][s]);                                \
      MFMA(acc1[2+nt], a1l, fhhh[nt][s]);                                \
      MFMA(acc1[0+nt], a0h, fhhl[nt][s]);                                \
      MFMA(acc1[2+nt], a1h, fhhl[nt][s]);                                \
      MFMA(acc2[0+nt], a0l, fhhl[nt][s]);                                \
      MFMA(acc2[2+nt], a1l, fhhl[nt][s]);                                \
    }                                                                    \
  }
// chunk c in LDS buf c&1; loads for c+1 issued before computing c (overlap).
// Safety: STAGE_WRITE(b) for chunk c+1 only after the sync that ended all
// reads of buf b (chunk c-1), and never concurrent with HCHUNK reads of the
// other buffer. Verified pairing below.
#define HPART_PIPE()                                                     \
  { f32x4 vh[4], vl[4];                                                  \
    STAGE_ISSUE(0)                                                       \
    VMWAIT; STAGE_WRITE(0) __syncthreads();                              \
    STAGE_ISSUE(1)                                                       \
    HCHUNK(0, 0)                                                         \
    VMWAIT; STAGE_WRITE(1) __syncthreads();                              \
    STAGE_ISSUE(2)                                                       \
    HCHUNK(1, 1)                                                         \
    VMWAIT; STAGE_WRITE(0) __syncthreads();                              \
    STAGE_ISSUE(3)                                                       \
    HCHUNK(0, 2)                                                         \
    VMWAIT; STAGE_WRITE(1) __syncthreads();                              \
    HCHUNK(1, 3) }

__global__ void __launch_bounds__(256, 1) lstm_seq2seq(
    const float* __restrict__ sig,   // [B,S,F]
    const int*   __restrict__ tgt,   // [B,T]
    const float* __restrict__ eWih,  // [2048,128]
    const float* __restrict__ eWhh,  // [2048,512]
    const float* __restrict__ eBih,  // [2048]
    const float* __restrict__ eBhh,  // [2048]
    const float* __restrict__ dWih,  // [2048,64]
    const float* __restrict__ dWhh,  // [2048,512]
    const float* __restrict__ dBih,  // [2048]
    const float* __restrict__ dBhh,  // [2048]
    const float* __restrict__ oW,    // [64,512]
    const float* __restrict__ oB,    // [64]
    float*       __restrict__ out,   // [B,T,V]
    unsigned char* __restrict__ ws)
{
  unsigned* flags  = (unsigned*)ws;            // 32 flags, 128B stride (4KB)
  unsigned* idxbuf = (unsigned*)(ws + 4096);
  f16* hhi[2] = { (f16*)(ws + 8192),   (f16*)(ws + 8192 + 65536) };
  f16* hlo[2] = { (f16*)(ws + 139264), (f16*)(ws + 139264 + 65536) };
  float* hf32[2] = { (float*)(ws + 270336), (float*)(ws + 270336 + 131072) };

  const int tid   = threadIdx.x;
  const int p     = blockIdx.x;     // WG owns h-dims [p*16, p*16+16) per gate
  const int w     = tid >> 6;
  const int lane  = tid & 63;
  const int q     = lane >> 4;      // MFMA quad
  const int mn    = lane & 15;
  const int q8    = q * 8;
  const int bhalf = w >> 1;
  const int dhalf = w & 1;
  const int r0    = bhalf*32 + mn;  // A rows for the two row-tiles
  const int r1    = r0 + 16;
  const int sr    = tid >> 2;       // staging: row 0..63
  const int sk    = tid & 3;        // staging: 16B-unit group

  __shared__ f16 xwh[64][136];      // eWih slice hi
  __shared__ f16 xwl[64][136];      // eWih slice lo (x2048)
  __shared__ f16 shi[2][64][136];   // staged h hi (chunk dbuf)
  __shared__ f16 slo[2][64][136];   // staged h lo
  __shared__ float gate_buf[4][64][17];
  __shared__ float bias_buf[4][16];

  // ---- encoder weights: W_hh hi/lo fragments in registers ----
  f16x8 fhhh[2][16], fhhl[2][16];
#pragma unroll
  for (int nt = 0; nt < 2; ++nt) {
    int dl  = dhalf*32 + nt*16 + mn;
    int row = (dl >> 4)*HH + p*16 + (dl & 15);
#pragma unroll
    for (int s = 0; s < 16; ++s)
      split8(eWhh + (size_t)row*HH + s*32 + q8, fhhh[nt][s], fhhl[nt][s]);
  }
  for (int idx = tid; idx < 64*128; idx += 256) {
    int dl = idx >> 7, k = idx & 127;
    int row = (dl >> 4)*HH + p*16 + (dl & 15);
    float x = eWih[row*FF + k];
    f16 a = (f16)x;
    xwh[dl][k] = a;
    xwl[dl][k] = (f16)((x - (float)a) * 2048.0f);
  }
  if (tid < 64) {
    int g = tid >> 4, kl = tid & 15;
    int r = g*HH + p*16 + kl;
    bias_buf[g][kl] = eBih[r] + eBhh[r];
  }
  if (p == 0 && tid < 64) st4f(idxbuf + tid, (unsigned)tgt[tid * TT]); // target[:,0]
  __syncthreads();

  float c_reg[4] = {0.f, 0.f, 0.f, 0.f};
  const int eb  = tid >> 2;
  const int ek0 = (tid & 3) * 4;
  const int off0 = eb*HH + p*16 + ek0;

  int cur = 0;                       // h double buffer (zeroed by memset = h0)
  const f32x4 zero4 = {0.f, 0.f, 0.f, 0.f};

  // ================= encoder: 1024 steps =================
  for (int t = 0; t < SS; ++t) {
    f32x4 acc0[4] = {zero4, zero4, zero4, zero4};
    f32x4 acc1[4] = {zero4, zero4, zero4, zero4};
    f32x4 acc2[4] = {zero4, zero4, zero4, zero4};

    // ---- x part (h-independent, overlaps other WGs finishing step t-1) ----
    const float* sb0 = sig + (size_t)r0*(SS*FF) + (size_t)t*FF;
    const float* sb1 = sb0 + (size_t)16*(SS*FF);
#pragma unroll
    for (int s = 0; s < 4; ++s) {
      f16x8 a0h, a0l, a1h, a1l;
      split8(sb0 + s*32 + q8, a0h, a0l);
      split8(sb1 + s*32 + q8, a1h, a1l);
#pragma unroll
      for (int nt = 0; nt < 2; ++nt) {
        int dl = dhalf*32 + nt*16 + mn;
        f16x8 bh = ldh8(&xwh[dl][s*32 + q8]);
        f16x8 bl = ldh8(&xwl[dl][s*32 + q8]);
        MFMA(acc0[0+nt], a0h, bh);  MFMA(acc0[2+nt], a1h, bh);
        MFMA(acc1[0+nt], a0l, bh);  MFMA(acc1[2+nt], a1l, bh);
        MFMA(acc1[0+nt], a0h, bl);  MFMA(acc1[2+nt], a1h, bl);
        MFMA(acc2[0+nt], a0l, bl);  MFMA(acc2[2+nt], a1l, bl);
      }
    }
    // ---- h(t) needed: wait, then staged pipelined h-part ----
    wait_flags(flags, (unsigned)t, lane);
    const f16* ghi = hhi[cur];
    const f16* glo = hlo[cur];
    HPART_PIPE()
    // gates -> LDS exchange (C/D: col=mn, row=q*4+r)
#pragma unroll
    for (int rt = 0; rt < 2; ++rt)
#pragma unroll
      for (int nt = 0; nt < 2; ++nt) {
        int i = rt*2 + nt;
#pragma unroll
        for (int r = 0; r < 4; ++r) {
          float g = acc0[i][r] + C1*acc1[i][r] + C2*acc2[i][r];
          gate_buf[dhalf*2 + nt][bhalf*32 + rt*16 + q*4 + r][mn] = g;
        }
      }
    __syncthreads();
    // LSTM cell (f32, precise libm)
    {
      union { f16 h[4]; u64 u; } ph, pl;
#pragma unroll
      for (int j = 0; j < 4; ++j) {
        int kl = ek0 + j;
        float gi = gate_buf[0][eb][kl] + bias_buf[0][kl];
        float gf = gate_buf[1][eb][kl] + bias_buf[1][kl];
        float gg = gate_buf[2][eb][kl] + bias_buf[2][kl];
        float go = gate_buf[3][eb][kl] + bias_buf[3][kl];
        float c  = sigmf_(gf)*c_reg[j] + sigmf_(gi)*tanhf(gg);
        float h  = sigmf_(go)*tanhf(c);
        c_reg[j] = c;
        f16 hh = (f16)h;
        ph.h[j] = hh;
        pl.h[j] = (f16)((h - (float)hh) * 2048.0f);
      }
      st8f(hhi[cur^1] + off0, ph.u);
      st8f(hlo[cur^1] + off0, pl.u);
    }
    VMWAIT;             // h stores acked at coherence point
    __syncthreads();    // whole WG done
    if (tid == 0) st4f(flags + (size_t)p*32, (unsigned)(t + 1));
    cur ^= 1;
  }

  // ================= decoder setup ====
#pragma unroll
  for (int nt = 0; nt < 2; ++nt) {
    int dl  = dhalf*32 + nt*16 + mn;
    int row = (dl >> 4)*HH + p*16 + (dl & 15);
#pragma unroll
    for (int s = 0; s < 16; ++s)
      split8(dWhh + (size_t)row*HH + s*32 + q8, fhhh[nt][s], fhhl[nt][s]);
  }
  __syncthreads();
  if (tid < 64) {
    int g = tid >> 4, kl = tid & 15;
    int r = g*HH + p*16 + kl;
    bias_buf[g][kl] = dBih[r] + dBhh[r];
  }
  __syncthreads();

  // ================= decoder: 64 steps =================
  float (*pbf)[520] = (float(*)[520])gate_buf;   // phase-B h scratch overlay
  for (int t = 0; t < TT; ++t) {
    // ---- phase A: cell. x = relu(one_hot(idx)) = one_hot -> column gather ----
    wait_flags(flags, (unsigned)(SS + 2*t), lane);
    f32x4 acc0[4] = {zero4, zero4, zero4, zero4};
    f32x4 acc1[4] = {zero4, zero4, zero4, zero4};
    f32x4 acc2[4] = {zero4, zero4, zero4, zero4};
    const f16* ghi = hhi[cur];
    const f16* glo = hlo[cur];
    HPART_PIPE()
#pragma unroll
    for (int rt = 0; rt < 2; ++rt)
#pragma unroll
      for (int nt = 0; nt < 2; ++nt) {
        int i = rt*2 + nt;
#pragma unroll
        for (int r = 0; r < 4; ++r) {
          float g = acc0[i][r] + C1*acc1[i][r] + C2*acc2[i][r];
          gate_buf[dhalf*2 + nt][bhalf*32 + rt*16 + q*4 + r][mn] = g;
        }
      }
    __syncthreads();
    {
      int ib = (int)ld4f(idxbuf + eb);
      union { f16 h[4]; u64 u; } ph, pl;
      union { float f[2]; u64 u; } pf0, pf1;
#pragma unroll
      for (int j = 0; j < 4; ++j) {
        int kl = ek0 + j;
        int rb = p*16 + kl;
        float gi = gate_buf[0][eb][kl] + bias_buf[0][kl] + dWih[(0*HH + rb)*VV + ib];
        float gf = gate_buf[1][eb][kl] + bias_buf[1][kl] + dWih[(1*HH + rb)*VV + ib];
        float gg = gate_buf[2][eb][kl] + bias_buf[2][kl] + dWih[(2*HH + rb)*VV + ib];
        float go = gate_buf[3][eb][kl] + bias_buf[3][kl] + dWih[(3*HH + rb)*VV + ib];
        float c  = sigmf_(gf)*c_reg[j] + sigmf_(gi)*tanhf(gg);
        float h  = sigmf_(go)*tanhf(c);
        c_reg[j] = c;
        f16 hh = (f16)h;
        ph.h[j] = hh;
        pl.h[j] = (f16)((h - (float)hh) * 2048.0f);
        if (j < 2) pf0.f[j] = h; else pf1.f[j-2] = h;
      }
      st8f(hhi[cur^1] + off0, ph.u);
      st8f(hlo[cur^1] + off0, pl.u);
      st8f(hf32[cur^1] + off0,     pf0.u);
      st8f(hf32[cur^1] + off0 + 2, pf1.u);
    }
    VMWAIT;
    __syncthreads();
    if (tid == 0) st4f(flags + (size_t)p*32, (unsigned)(SS + 2*t + 1));
    int nxt = cur ^ 1;

    // ---- phase B: stage this WG's 2 hf32 rows to LDS, then f64 logits ----
    wait_flags(flags, (unsigned)(SS + 2*t + 1), lane);
    {
      int row2 = tid >> 7, un = tid & 127;
      f32x4 hv = ld16f(hf32[nxt] + (size_t)(p*2 + row2)*HH + un*4);
      VMWAIT;
      *(f32x4*)&pbf[row2][un*4] = hv;
    }
    __syncthreads();
    if (w < 2) {
      int b = p*2 + w;
      int v = lane;
      const float* wr = oW + v*HH;
      double acc = 0.0;
#pragma unroll 4
      for (int kc = 0; kc < 128; ++kc) {
        f32x4 hv = *(const f32x4*)&pbf[w][kc*4];
        f32x4 wv = *(const f32x4*)(wr + kc*4);
        acc += (double)hv[0]*(double)wv[0] + (double)hv[1]*(double)wv[1]
             + (double)hv[2]*(double)wv[2] + (double)hv[3]*(double)wv[3];
      }
      double l = acc + (double)oB[v];
      double mx = l; int ai = v;
#pragma unroll
      for (int o = 32; o > 0; o >>= 1) {
        double om = __shfl_xor(mx, o, 64);
        int    oi = __shfl_xor(ai, o, 64);
        if (om > mx || (om == mx && oi < ai)) { mx = om; ai = oi; }
      }
      double se = exp(l - mx);
#pragma unroll
      for (int o = 32; o > 0; o >>= 1) se += __shfl_xor(se, o, 64);
      double lse = mx + log(se);
      out[((size_t)b*TT + t)*VV + v] = (float)(l - lse);
      if (lane == 0) st4f(idxbuf + b, (unsigned)ai);
    }
    VMWAIT;
    __syncthreads();
    if (tid == 0) st4f(flags + (size_t)p*32, (unsigned)(SS + 2*t + 2));
    cur = nxt;
  }
}

extern "C" void kernel_launch(void* const* d_in, const int* in_sizes, int n_in,
                              void* d_out, int out_size, void* d_ws, size_t ws_size,
                              hipStream_t stream) {
  (void)in_sizes; (void)n_in; (void)out_size; (void)ws_size;
  // zero: flags + idxbuf + h16 hi/lo dbuf + hf32 dbuf (ws re-poisoned 0xAA
  // before every timed launch -> must zero every call)
  size_t zbytes = 532480;
  hipMemsetAsync(d_ws, 0, zbytes, stream);
  lstm_seq2seq<<<dim3(NWG), dim3(256), 0, stream>>>(
      (const float*)d_in[0],  (const int*)d_in[1],
      (const float*)d_in[2],  (const float*)d_in[3],
      (const float*)d_in[4],  (const float*)d_in[5],
      (const float*)d_in[6],  (const float*)d_in[7],
      (const float*)d_in[8],  (const float*)d_in[9],
      (const float*)d_in[10], (const float*)d_in[11],
      (float*)d_out, (unsigned char*)d_ws);
}